// Round 7
// baseline (92.569 us; speedup 1.0000x reference)
//
#include <hip/hip_runtime.h>

#define B_   256
#define E_   64
#define G_   2000
#define P_   512
#define K2   2048      // G padded to multiple of BK (xb zero-filled)
#define BK   32
#define NS   (K2/BK)   // 64 K-steps
#define PT   64        // p columns per block

typedef __bf16 bf16x8 __attribute__((ext_vector_type(8)));
typedef float floatx16 __attribute__((ext_vector_type(16)));
typedef unsigned int u32;

__global__ __launch_bounds__(256)
void cvt_x_kernel(const float* __restrict__ x, __bf16* __restrict__ xb) {
    int col = blockIdx.x * 256 + threadIdx.x;   // 0..2047
    int row = blockIdx.y;
    float v = (col < G_) ? x[(size_t)row * G_ + col] : 0.f;
    xb[(size_t)row * K2 + col] = (__bf16)v;
}

__device__ __forceinline__ void gll16(const void* g, void* l) {
    __builtin_amdgcn_global_load_lds(
        (const __attribute__((address_space(1))) u32*)(uintptr_t)g,
        (__attribute__((address_space(3))) u32*)(uintptr_t)l,
        16, 0, 0);
}

// Structure (per 256-thread block, PT=64 p-cols, BK=32, 64 steps):
//  - A (=x bf16) via gll16: [2][256r][32k], 64B rows, chunk c of row r holds
//    global chunk c ^ ((r>>1)&3). 4 gll16/wave/step.
//  - W,M: per-thread coalesced strided dword gathers to REGISTERS (lane=p,
//    octet=wave), depth-2 (issued for step s+2). mul+cvt in reg, ONE
//    ds_write_b128/wave into bf16 B-tile bblds[2][64p][32k] (same XOR swz).
//  - compute: per wave 4 B b128 + 4 A b128 reads + 8 MFMA 32x32x16.
//  - raw s_barrier + counted vmcnt(16): retires A(s) glls, leaves WM(s+1)
//    gathers in flight across the barrier. Never vmcnt(0) until the tail.
template<bool USE_WS>
__global__ __launch_bounds__(256, 2)
void masked_gemm_kernel(const float* __restrict__ x,
                        const __bf16* __restrict__ xb,
                        const float* __restrict__ weight,
                        const float* __restrict__ bias,
                        const float* __restrict__ mask,
                        float* __restrict__ out)
{
    __shared__ __attribute__((aligned(128))) __bf16 alds[2][B_ * BK];   // 2x16KB
    __shared__ __attribute__((aligned(128))) __bf16 bblds[2][PT * BK];  // 2x4KB

    const int tid  = threadIdx.x;
    const int lane = tid & 63;
    const int wv   = tid >> 6;           // wave owns rows wv*64..wv*64+63
    const int ln   = lane & 31;
    const int hi   = lane >> 5;          // k-octet half within kk

    const int bid = blockIdx.x;          // 512 blocks
    const int pt  = bid & 7;             // p-tile -> XCD (mask/xb slabs L2-hot)
    const int e   = bid >> 3;            // expert 0..63
    const int p0  = pt * PT;

    const float* wcol = weight + (size_t)e * G_ * P_ + p0 + lane;  // lane = p
    const float* mcol = mask + p0 + lane;

    const int arow  = lane >> 2;         // A staging: row in 16-row group
    const int aslot = lane & 3;          // A staging: 16B chunk slot
    // bb write: row p=lane, phys chunk = wv ^ ((lane>>1)&3), bf16 index:
    const int bbw = lane * BK + ((wv ^ ((lane >> 1) & 3)) << 3);

    floatx16 acc[2][2];
    #pragma unroll
    for (int i = 0; i < 2; ++i)
        #pragma unroll
        for (int j = 0; j < 2; ++j) acc[i][j] = (floatx16)0.f;

    auto stageA = [&](int kb, int ab) {
        #pragma unroll
        for (int i = 0; i < 4; ++i) {
            const int r0  = wv * 64 + i * 16;
            const int row = r0 + arow;
            const int c   = aslot ^ ((row >> 1) & 3);
            if (USE_WS) {
                gll16(xb + (size_t)row * K2 + kb + c * 8, (void*)&alds[ab][r0 * BK]);
            } else {
                const int k0 = kb + c * 8;
                bf16x8 v;
                #pragma unroll
                for (int j = 0; j < 8; ++j)
                    v[j] = (k0 + j < G_) ? (__bf16)x[(size_t)row * G_ + k0 + j] : (__bf16)0.f;
                *(bf16x8*)&alds[ab][row * BK + aslot * 8] = v;
            }
        }
    };

#define GATHER_WM(KB2, W, M)                                            \
    { _Pragma("unroll")                                                  \
      for (int j = 0; j < 8; ++j) {                                      \
          int g = (KB2) + wv * 8 + j;                                    \
          if (g > G_ - 1) g = G_ - 1;   /* tail clamp: A k-tail == 0 */  \
          W[j] = wcol[(size_t)g * P_];                                   \
          M[j] = mcol[(size_t)g * P_];                                   \
      } }

#define CVT_WRITE_BB(W, M, BBN)                                          \
    { bf16x8 hv;                                                         \
      _Pragma("unroll")                                                  \
      for (int j = 0; j < 8; ++j) hv[j] = (__bf16)(W[j] * M[j]);         \
      *(bf16x8*)&bblds[BBN][bbw] = hv; }

#define COMPUTE(AB)                                                      \
    { _Pragma("unroll")                                                  \
      for (int kk = 0; kk < 2; ++kk) {                                   \
        bf16x8 bfrag[2];                                                 \
        _Pragma("unroll")                                                \
        for (int ni = 0; ni < 2; ++ni) {                                 \
            const int pl = ni * 32 + ln;                                 \
            bfrag[ni] = *(const bf16x8*)&bblds[AB][pl * BK +             \
                          (((kk * 2 + hi) ^ ((pl >> 1) & 3)) << 3)];     \
        }                                                                \
        _Pragma("unroll")                                                \
        for (int mi = 0; mi < 2; ++mi) {                                 \
            const int row = wv * 64 + mi * 32 + ln;                      \
            const int c   = (kk * 2 + hi) ^ ((row >> 1) & 3);            \
            bf16x8 a = *(const bf16x8*)&alds[AB][row * BK + c * 8];      \
            _Pragma("unroll")                                            \
            for (int ni = 0; ni < 2; ++ni)                               \
                acc[mi][ni] = __builtin_amdgcn_mfma_f32_32x32x16_bf16(   \
                                  a, bfrag[ni], acc[mi][ni], 0, 0, 0);   \
      } } }

#define STEP(S, WI, MI, WU, MU, PAR)                                     \
    {                                                                    \
      if ((S) + 2 < NS) { asm volatile("s_waitcnt vmcnt(16) lgkmcnt(0)" ::: "memory"); } \
      else              { asm volatile("s_waitcnt vmcnt(0) lgkmcnt(0)" ::: "memory"); }  \
      __builtin_amdgcn_s_barrier();                                      \
      __builtin_amdgcn_sched_barrier(0);                                 \
      if ((S) + 1 < NS) stageA(((S) + 1) * BK, (PAR) ^ 1);               \
      if ((S) + 2 < NS) GATHER_WM(((S) + 2) * BK, WI, MI);               \
      __builtin_amdgcn_sched_barrier(0);                                 \
      COMPUTE(PAR);                                                      \
      if ((S) + 1 < NS) CVT_WRITE_BB(WU, MU, (PAR) ^ 1);                 \
    }

    float w0[8], m0[8], w1[8], m1[8];

    // ---- prologue: A(0) glls; WM(0)->regs->bb[0]; WM(1)->regs ----
    stageA(0, 0);
    GATHER_WM(0, w0, m0);
    CVT_WRITE_BB(w0, m0, 0);     // compiler waits WM(0) (drains A(0) too; one-time)
    GATHER_WM(BK, w1, m1);       // WM(1) in flight across first barrier

    // steady state at top of iter s: outstanding = A(s)[4] + WM(s+1)[16]
    for (int it = 0; it < NS / 2; ++it) {
        const int s = it * 2;
        STEP(s,     w0, m0, w1, m1, 0);   // issue WM(s+2)->set0, consume set1
        STEP(s + 1, w1, m1, w0, m0, 1);
    }

    // ---- epilogue: D col n=p=lane&31, row m=(r&3)+8*(r>>2)+4*hi ----
    const float bv0 = bias[e * P_ + p0 + ln];
    const float bv1 = bias[e * P_ + p0 + 32 + ln];
    #pragma unroll
    for (int mi = 0; mi < 2; ++mi)
        #pragma unroll
        for (int ni = 0; ni < 2; ++ni) {
            const float bv = ni ? bv1 : bv0;
            #pragma unroll
            for (int r = 0; r < 16; ++r) {
                const int b = wv * 64 + mi * 32 + (r & 3) + 8 * (r >> 2) + 4 * hi;
                __builtin_nontemporal_store(acc[mi][ni][r] + bv,
                    &out[(size_t)b * (E_ * P_) + (size_t)e * P_ + p0 + ni * 32 + ln]);
            }
        }
}

extern "C" void kernel_launch(void* const* d_in, const int* in_sizes, int n_in,
                              void* d_out, int out_size, void* d_ws, size_t ws_size,
                              hipStream_t stream) {
    const float* x      = (const float*)d_in[0];
    const float* weight = (const float*)d_in[1];
    const float* bias   = (const float*)d_in[2];
    const float* mask   = (const float*)d_in[3];
    float* out = (float*)d_out;

    const size_t xb_bytes = (size_t)B_ * K2 * sizeof(__bf16);
    if (ws_size >= xb_bytes) {
        __bf16* xb = (__bf16*)d_ws;
        dim3 g1(K2 / 256, B_);
        cvt_x_kernel<<<g1, dim3(256), 0, stream>>>(x, xb);
        masked_gemm_kernel<true><<<dim3(512), dim3(256), 0, stream>>>(x, xb, weight, bias, mask, out);
    } else {
        masked_gemm_kernel<false><<<dim3(512), dim3(256), 0, stream>>>(x, nullptr, weight, bias, mask, out);
    }
}